// Round 1
// baseline (106.664 us; speedup 1.0000x reference)
//
#include <hip/hip_runtime.h>
#include <hip/hip_bf16.h>

// MILAttentionPool: B=32, L=2048, D=512, H=256, K=4
// out[b, k*512+d] = sum_l softmax_l(logit[b,l,k]) * x[b*L+l, d]
// logit = (tanh(x@W1+b1)*sigmoid(x@W3+b3)) @ W2   (+b2 cancels in softmax)

typedef short  bf16x8 __attribute__((ext_vector_type(8)));
typedef float  f32x4  __attribute__((ext_vector_type(4)));

#define N_TOT   65536
#define D_IN    512
#define H_DIM   256
#define B_BAGS  32
#define L_BAG   2048

#define BM      128
#define BKQ     32
#define NKT     (D_IN / BKQ)   // 16
#define PADK    40             // LDS row stride in shorts (80B -> 2-way-free banks)

__device__ __forceinline__ short f2bf(float f) {
  union { __hip_bfloat16 h; short s; } u;
  u.h = __float2bfloat16(f);
  return u.s;
}

// ---------------- k0: W1/W3 -> bf16, blocked-transposed [K/32][256][32] ----------------
__global__ __launch_bounds__(256) void k_prep_w(const float* __restrict__ W1,
                                                const float* __restrict__ W3,
                                                short* __restrict__ w1b,
                                                short* __restrict__ w3b) {
  int idx = blockIdx.x * 256 + threadIdx.x;      // 0 .. 262143
  int which = idx >> 17;
  int rem = idx & 131071;
  int k = rem >> 8;          // 0..511
  int n = rem & 255;         // 0..255
  const float* src = which ? W3 : W1;
  short* dst = which ? w3b : w1b;
  dst[(k >> 5) * 8192 + n * 32 + (k & 31)] = f2bf(src[k * H_DIM + n]);
}

// ---------------- k1: fused gate GEMMs (bf16 MFMA) + logits = gate@W2 ----------------
__global__ __launch_bounds__(512, 2) void k_gate_logits(
    const float* __restrict__ x,
    const short* __restrict__ w1b, const short* __restrict__ w3b,
    const float* __restrict__ b1, const float* __restrict__ b3,
    const float* __restrict__ W2,
    float* __restrict__ logits)
{
  __shared__ __align__(16) short xs [BM * PADK];        // 10240 B
  __shared__ __align__(16) short w1s[H_DIM * PADK];     // 20480 B
  __shared__ __align__(16) short w3s[H_DIM * PADK];     // 20480 B
  __shared__ __align__(16) float w2s[H_DIM * 4];        //  4096 B
  __shared__ float lpart[4][BM][4];                     //  8192 B   (total 63488)

  const int tid  = threadIdx.x;
  const int lane = tid & 63;
  const int wid  = tid >> 6;
  const int wrow = wid >> 2;       // 0..1  (64-row band)
  const int wcol = wid & 3;        // 0..3  (64-col band)
  const long row0 = (long)blockIdx.x * BM;

  if (tid < 256) ((f32x4*)w2s)[tid] = ((const f32x4*)W2)[tid];

  f32x4 acc1[4][4], acc3[4][4];
  #pragma unroll
  for (int m = 0; m < 4; ++m)
    #pragma unroll
    for (int n = 0; n < 4; ++n) {
      acc1[m][n] = (f32x4){0.f, 0.f, 0.f, 0.f};
      acc3[m][n] = (f32x4){0.f, 0.f, 0.f, 0.f};
    }

  const int xr = tid >> 2;          // 0..127
  const int xc = (tid & 3) * 8;     // 0,8,16,24
  const int wn = tid >> 1;          // 0..255
  const int wo = (tid & 1) * 16;    // 0,16

  for (int kt = 0; kt < NKT; ++kt) {
    // stage x tile: 128 rows x 32 cols fp32 -> bf16
    {
      const float* src = x + (row0 + xr) * D_IN + kt * BKQ + xc;
      float4 f0 = *(const float4*)(src);
      float4 f1 = *(const float4*)(src + 4);
      bf16x8 v;
      v[0] = f2bf(f0.x); v[1] = f2bf(f0.y); v[2] = f2bf(f0.z); v[3] = f2bf(f0.w);
      v[4] = f2bf(f1.x); v[5] = f2bf(f1.y); v[6] = f2bf(f1.z); v[7] = f2bf(f1.w);
      *(bf16x8*)&xs[xr * PADK + xc] = v;
    }
    // stage W tiles: contiguous 16KB each (blocked layout), 32B/thread/W
    {
      const short* s1 = w1b + kt * 8192 + tid * 16;
      const short* s3 = w3b + kt * 8192 + tid * 16;
      bf16x8 a0 = *(const bf16x8*)s1;
      bf16x8 a1 = *(const bf16x8*)(s1 + 8);
      bf16x8 c0 = *(const bf16x8*)s3;
      bf16x8 c1 = *(const bf16x8*)(s3 + 8);
      *(bf16x8*)&w1s[wn * PADK + wo]     = a0;
      *(bf16x8*)&w1s[wn * PADK + wo + 8] = a1;
      *(bf16x8*)&w3s[wn * PADK + wo]     = c0;
      *(bf16x8*)&w3s[wn * PADK + wo + 8] = c1;
    }
    __syncthreads();

    const int koff  = (lane >> 4) * 8;
    const int rbase = wrow * 64 + (lane & 15);
    const int cbase = wcol * 64 + (lane & 15);
    bf16x8 af[4], bfa[4], bfb[4];
    #pragma unroll
    for (int m = 0; m < 4; ++m)
      af[m] = *(const bf16x8*)&xs[(rbase + m * 16) * PADK + koff];
    #pragma unroll
    for (int n = 0; n < 4; ++n) {
      bfa[n] = *(const bf16x8*)&w1s[(cbase + n * 16) * PADK + koff];
      bfb[n] = *(const bf16x8*)&w3s[(cbase + n * 16) * PADK + koff];
    }
    #pragma unroll
    for (int m = 0; m < 4; ++m)
      #pragma unroll
      for (int n = 0; n < 4; ++n) {
        acc1[m][n] = __builtin_amdgcn_mfma_f32_16x16x32_bf16(af[m], bfa[n], acc1[m][n], 0, 0, 0);
        acc3[m][n] = __builtin_amdgcn_mfma_f32_16x16x32_bf16(af[m], bfb[n], acc3[m][n], 0, 0, 0);
      }
    __syncthreads();
  }

  // epilogue: gate = tanh(h1+b1)*sigmoid(h3+b3); partial logits = gate @ W2
  float b1v[4], b3v[4];
  f32x4 wv[4];
  #pragma unroll
  for (int n = 0; n < 4; ++n) {
    int c = wcol * 64 + n * 16 + (lane & 15);
    b1v[n] = b1[c];
    b3v[n] = b3[c];
    wv[n] = *(const f32x4*)&w2s[c * 4];
  }
  float pl[4][4][4];
  #pragma unroll
  for (int m = 0; m < 4; ++m)
    #pragma unroll
    for (int j = 0; j < 4; ++j)
      #pragma unroll
      for (int kk = 0; kk < 4; ++kk) pl[m][j][kk] = 0.f;

  #pragma unroll
  for (int m = 0; m < 4; ++m)
    #pragma unroll
    for (int n = 0; n < 4; ++n)
      #pragma unroll
      for (int j = 0; j < 4; ++j) {
        float h1 = acc1[m][n][j] + b1v[n];
        float h3 = acc3[m][n][j] + b3v[n];
        float th = 1.f - __fdividef(2.f, __expf(2.f * h1) + 1.f);
        float sg = __fdividef(1.f, 1.f + __expf(-h3));
        float g = th * sg;
        pl[m][j][0] += g * wv[n][0];
        pl[m][j][1] += g * wv[n][1];
        pl[m][j][2] += g * wv[n][2];
        pl[m][j][3] += g * wv[n][3];
      }

  // reduce over the 16 lanes (columns) of each lane-group
  #pragma unroll
  for (int off = 1; off < 16; off <<= 1)
    #pragma unroll
    for (int m = 0; m < 4; ++m)
      #pragma unroll
      for (int j = 0; j < 4; ++j)
        #pragma unroll
        for (int kk = 0; kk < 4; ++kk)
          pl[m][j][kk] += __shfl_xor(pl[m][j][kk], off);

  if ((lane & 15) == 0) {
    int lg = lane >> 4;
    #pragma unroll
    for (int m = 0; m < 4; ++m)
      #pragma unroll
      for (int j = 0; j < 4; ++j)
        #pragma unroll
        for (int kk = 0; kk < 4; ++kk)
          lpart[wcol][wrow * 64 + m * 16 + lg * 4 + j][kk] = pl[m][j][kk];
  }
  __syncthreads();

  {
    int r = tid >> 2, kk = tid & 3;   // 512 threads = 128 rows x 4
    float v = lpart[0][r][kk] + lpart[1][r][kk] + lpart[2][r][kk] + lpart[3][r][kk];
    logits[(row0 + r) * 4 + kk] = v;
  }
}

// ---------------- k2: per-(bag, head) softmax max & sum ----------------
__global__ __launch_bounds__(256) void k_softmax_stats(const float* __restrict__ logits,
                                                       float* __restrict__ mx,
                                                       float* __restrict__ sm) {
  const int b = blockIdx.x, tid = threadIdx.x;
  const int lane = tid & 63, wid = tid >> 6;
  const float4* L = (const float4*)logits + (long)b * L_BAG;

  float m0 = -3e38f, m1 = m0, m2 = m0, m3 = m0;
  #pragma unroll
  for (int i = 0; i < 8; ++i) {
    float4 v = L[i * 256 + tid];
    m0 = fmaxf(m0, v.x); m1 = fmaxf(m1, v.y); m2 = fmaxf(m2, v.z); m3 = fmaxf(m3, v.w);
  }
  #pragma unroll
  for (int o = 1; o < 64; o <<= 1) {
    m0 = fmaxf(m0, __shfl_xor(m0, o)); m1 = fmaxf(m1, __shfl_xor(m1, o));
    m2 = fmaxf(m2, __shfl_xor(m2, o)); m3 = fmaxf(m3, __shfl_xor(m3, o));
  }
  __shared__ float wr[4][4];
  __shared__ float bm[4];
  if (lane == 0) { wr[wid][0] = m0; wr[wid][1] = m1; wr[wid][2] = m2; wr[wid][3] = m3; }
  __syncthreads();
  if (tid < 4) bm[tid] = fmaxf(fmaxf(wr[0][tid], wr[1][tid]), fmaxf(wr[2][tid], wr[3][tid]));
  __syncthreads();
  m0 = bm[0]; m1 = bm[1]; m2 = bm[2]; m3 = bm[3];

  float s0 = 0.f, s1 = 0.f, s2 = 0.f, s3 = 0.f;
  #pragma unroll
  for (int i = 0; i < 8; ++i) {
    float4 v = L[i * 256 + tid];
    s0 += __expf(v.x - m0); s1 += __expf(v.y - m1);
    s2 += __expf(v.z - m2); s3 += __expf(v.w - m3);
  }
  #pragma unroll
  for (int o = 1; o < 64; o <<= 1) {
    s0 += __shfl_xor(s0, o); s1 += __shfl_xor(s1, o);
    s2 += __shfl_xor(s2, o); s3 += __shfl_xor(s3, o);
  }
  __syncthreads();
  if (lane == 0) { wr[wid][0] = s0; wr[wid][1] = s1; wr[wid][2] = s2; wr[wid][3] = s3; }
  __syncthreads();
  if (tid < 4) {
    mx[b * 4 + tid] = bm[tid];
    sm[b * 4 + tid] = wr[0][tid] + wr[1][tid] + wr[2][tid] + wr[3][tid];
  }
}

// ---------------- k3: partial weighted sums over 128-row chunks ----------------
__global__ __launch_bounds__(128) void k_weighted_partial(const float* __restrict__ x,
                                                          const float* __restrict__ logits,
                                                          const float* __restrict__ mx,
                                                          float* __restrict__ part) {
  const int chunk = blockIdx.x;   // 0..15
  const int b = blockIdx.y;       // 0..31
  const int tid = threadIdx.x;    // 0..127
  const long l0 = (long)b * L_BAG + chunk * 128;

  __shared__ float ep[128][4];
  {
    float4 lg = ((const float4*)logits)[l0 + tid];
    ep[tid][0] = __expf(lg.x - mx[b * 4 + 0]);
    ep[tid][1] = __expf(lg.y - mx[b * 4 + 1]);
    ep[tid][2] = __expf(lg.z - mx[b * 4 + 2]);
    ep[tid][3] = __expf(lg.w - mx[b * 4 + 3]);
  }
  __syncthreads();

  float4 a0 = {0,0,0,0}, a1 = {0,0,0,0}, a2 = {0,0,0,0}, a3 = {0,0,0,0};
  const float4* xp = (const float4*)(x + l0 * D_IN) + tid;
  #pragma unroll 4
  for (int l = 0; l < 128; ++l) {
    float4 xv = xp[l * 128];
    float e0 = ep[l][0], e1 = ep[l][1], e2 = ep[l][2], e3 = ep[l][3];
    a0.x += e0 * xv.x; a0.y += e0 * xv.y; a0.z += e0 * xv.z; a0.w += e0 * xv.w;
    a1.x += e1 * xv.x; a1.y += e1 * xv.y; a1.z += e1 * xv.z; a1.w += e1 * xv.w;
    a2.x += e2 * xv.x; a2.y += e2 * xv.y; a2.z += e2 * xv.z; a2.w += e2 * xv.w;
    a3.x += e3 * xv.x; a3.y += e3 * xv.y; a3.z += e3 * xv.z; a3.w += e3 * xv.w;
  }
  long base = ((long)chunk * 32 + b) * 2048 + tid * 4;
  *(float4*)&part[base +    0] = a0;
  *(float4*)&part[base +  512] = a1;
  *(float4*)&part[base + 1024] = a2;
  *(float4*)&part[base + 1536] = a3;
}

// ---------------- k4: reduce chunks, divide by softmax sum ----------------
__global__ __launch_bounds__(256) void k_finalize(const float* __restrict__ part,
                                                  const float* __restrict__ sm,
                                                  float* __restrict__ out) {
  int idx = blockIdx.x * 256 + threadIdx.x;  // 0..65535 = b*2048 + k*512 + d
  int b = idx >> 11, k = (idx >> 9) & 3;
  float s = 0.f;
  #pragma unroll
  for (int c = 0; c < 16; ++c) s += part[c * 65536 + idx];
  out[idx] = s / sm[b * 4 + k];
}

extern "C" void kernel_launch(void* const* d_in, const int* in_sizes, int n_in,
                              void* d_out, int out_size, void* d_ws, size_t ws_size,
                              hipStream_t stream) {
  const float* x  = (const float*)d_in[0];
  const float* W1 = (const float*)d_in[1];
  const float* b1 = (const float*)d_in[2];
  const float* W3 = (const float*)d_in[3];
  const float* b3 = (const float*)d_in[4];
  const float* W2 = (const float*)d_in[5];
  // d_in[6] = b2: constant over softmax axis -> cancels; d_in[7] = bag_lengths: shapes only
  float* out = (float*)d_out;

  char* ws = (char*)d_ws;                       // ~5.6 MB used
  short* w1b    = (short*)(ws + 0);             // 256 KB
  short* w3b    = (short*)(ws + 262144);        // 256 KB
  float* logits = (float*)(ws + 524288);        // 1 MB
  float* mx     = (float*)(ws + 1572864);       // 512 B
  float* sm     = (float*)(ws + 1573376);       // 512 B
  float* part   = (float*)(ws + 1573888);       // 4 MB

  hipLaunchKernelGGL(k_prep_w,          dim3(1024),    dim3(256), 0, stream, W1, W3, w1b, w3b);
  hipLaunchKernelGGL(k_gate_logits,     dim3(512),     dim3(512), 0, stream, x, w1b, w3b, b1, b3, W2, logits);
  hipLaunchKernelGGL(k_softmax_stats,   dim3(32),      dim3(256), 0, stream, logits, mx, sm);
  hipLaunchKernelGGL(k_weighted_partial,dim3(16, 32),  dim3(128), 0, stream, x, logits, mx, part);
  hipLaunchKernelGGL(k_finalize,        dim3(256),     dim3(256), 0, stream, part, sm, out);
}